// Round 1
// baseline (877.531 us; speedup 1.0000x reference)
//
#include <hip/hip_runtime.h>
#include <stdint.h>

#define NUM_SEQS 4
#define SEQ_LEN  4096
#define HIDDEN   2048
#define CONV_DIM 2048
#define NTOK     (NUM_SEQS * SEQ_LEN)
#define N3D      (3 * CONV_DIM)

typedef unsigned short u16;
typedef unsigned int   u32;
typedef __bf16 bf16x8 __attribute__((ext_vector_type(8)));
typedef float  f32x16 __attribute__((ext_vector_type(16)));

__device__ __forceinline__ u16 f2bf(float f) {
  union { float f; u32 u; } v; v.f = f;
  u32 u = v.u;
  u += 0x7fffu + ((u >> 16) & 1u);   // round-to-nearest-even
  return (u16)(u >> 16);
}

__device__ __forceinline__ void async16(const void* g, void* l) {
  __builtin_amdgcn_global_load_lds(
      (const __attribute__((address_space(1))) u32*)g,
      (__attribute__((address_space(3))) u32*)l, 16, 0, 0);
}

// ---------------- fp32 -> bf16 cast (vectorized) ----------------
__global__ __launch_bounds__(256) void cast_f32_bf16(
    const float* __restrict__ in, u16* __restrict__ out, int n4)
{
  int i = blockIdx.x * 256 + threadIdx.x;
  if (i >= n4) return;
  float4 f = ((const float4*)in)[i];
  ushort4 o;
  o.x = f2bf(f.x); o.y = f2bf(f.y); o.z = f2bf(f.z); o.w = f2bf(f.w);
  ((ushort4*)out)[i] = o;
}

// ---------------- bf16 GEMM, C = A[M,K] * B[N,K]^T ----------------
// 256x256 tile, BK=64, 8 waves (2M x 4N), per-wave 128x64 output as 4x2
// tiles of v_mfma_f32_32x32x16_bf16 (verified frag layouts from prior kernel:
// A/B frag: X[row=lane&31][k=8*(lane>>5)+j]; C/D: col=lane&31,
// row=(r&3)+8*(r>>2)+4*(lane>>5)).
//
// 8-phase schedule (T3+T4), 2 K-tiles per 8 phases, double-buffered LDS
// (128 KiB total). Per K-tile, 4 phases = C-quadrants (qm,nt):
//   p1:(0,0) reads A qm0 (8x ds_read_b128) + B nt0 (4x)
//   p2:(0,1) reads B nt1 (4x)
//   p3:(1,1) reads A qm1 (8x)
//   p4:(1,0) no reads; s_waitcnt vmcnt(4) checkpoint
// Staging (1 half-tile = 2 global_load_lds per thread, per phase):
//   p1: A-half0(t+1)  p2: A-half1(t+1)   (other buffer; its old A reads
//                                          drained at t-1's p3)
//   p3: B-half0(t+2)  p4: B-half1(t+2)   (this buffer; tile t's B reads
//                                          drained at p2's wait + barrier)
// vmcnt(4) at p4 leaves exactly B0/B1(t+2) in flight => tile t+1 landed.
// LDS granule swizzle: physical granule gp = logical ^ (row&7); applied on
// the GLOBAL source address (global_load_lds writes linearly) and on the
// ds_read address (both-sides involution). 8 consecutive lanes hit all 8
// granule slots = all 32 banks (conflict-free).
template<bool OUT_BF16>
__global__ __launch_bounds__(512, 2) void gemm256_bt(
    const u16* __restrict__ A, const u16* __restrict__ B, void* __restrict__ Cv,
    const int M, const int N, const int K)
{
  __shared__ u16 sm[65536];            // A: [0,32768) u16, B: [32768,65536)
  u16* ldsA = &sm[0];
  u16* ldsB = &sm[32768];

  const int tid  = threadIdx.x;
  const int lane = tid & 63;
  const int wave = tid >> 6;
  const int l32  = lane & 31;
  const int hl   = lane >> 5;
  const int wm   = wave >> 2;          // 0..1
  const int wn   = wave & 3;           // 0..3
  (void)M;

  // T1: bijective XCD swizzle (nwg % 8 == 0 for all our launches)
  const int gx  = gridDim.x;
  const int nwg = gx * gridDim.y;
  const int orig = blockIdx.y * gx + blockIdx.x;
  const int cpx  = nwg >> 3;
  const int swz  = (orig & 7) * cpx + (orig >> 3);
  const int nBase = (swz % gx) * 256;
  const int mBase = (swz / gx) * 256;

  const int NT = K >> 6;               // K-tiles of 64

  // ---- staging geometry: thread handles chunks tid and tid+512 of a half ----
  const int rowS = tid >> 3;                  // 0..63 (chunk1 row = rowS+64)
  const int gsel = (tid & 7) ^ (rowS & 7);    // swizzled source granule
  const u16* aTB = A + (size_t)(mBase + rowS) * K + gsel * 8;
  const u16* bTB = B + (size_t)(nBase + rowS) * K + gsel * 8;
  const size_t C1 = (size_t)64 * K;           // +64 rows for chunk 1

#define STAGE(ldsO, gBase, tl, h) do {                                        \
    const int _b = (tl) & 1;                                                  \
    u16* _d = (ldsO) + _b * 16384 + (h) * 8192 + tid * 8;                     \
    const u16* _s = (gBase) + (size_t)(h) * 128 * K + (size_t)(tl) * 64;      \
    async16(_s, _d);                                                          \
    async16(_s + C1, _d + 4096);                                              \
  } while (0)

  // ---- fragment-read geometry ----
  const int aRowU = (wm * 128 + l32) * 64;    // u16 row base within buffer
  const int bRowU = (wn * 64  + l32) * 64;
  int gpo[4];
#pragma unroll
  for (int ks = 0; ks < 4; ++ks) gpo[ks] = ((ks * 2 + hl) ^ (l32 & 7)) * 8;

#define LDA(mt, ks, b) (*(const bf16x8*)&ldsA[(b) * 16384 + aRowU + (mt) * 2048 + gpo[ks]])
#define LDB(nt, ks, b) (*(const bf16x8*)&ldsB[(b) * 16384 + bRowU + (nt) * 2048 + gpo[ks]])

  f32x16 acc[4][2];
#pragma unroll
  for (int i = 0; i < 4; ++i)
#pragma unroll
    for (int j = 0; j < 2; ++j)
#pragma unroll
      for (int r = 0; r < 16; ++r) acc[i][j][r] = 0.f;

  // ---- prologue: tile0 (A0,A1,B0,B1) + tile1 (B0,B1); oldest 8 = tile0 ----
  STAGE(ldsA, aTB, 0, 0); STAGE(ldsA, aTB, 0, 1);
  STAGE(ldsB, bTB, 0, 0); STAGE(ldsB, bTB, 0, 1);
  STAGE(ldsB, bTB, 1, 0); STAGE(ldsB, bTB, 1, 1);
  asm volatile("s_waitcnt vmcnt(4)" ::: "memory");
  __builtin_amdgcn_s_barrier();
  __builtin_amdgcn_sched_barrier(0);

  bf16x8 aF[2][4], bF[2][4];

#pragma unroll 2
  for (int t = 0; t < NT; ++t) {
    const int buf = t & 1;

    // ---------- phase 1: quadrant (qm0, nt0) ----------
    if (t + 1 < NT) STAGE(ldsA, aTB, t + 1, 0);
#pragma unroll
    for (int ks = 0; ks < 4; ++ks) {
      aF[0][ks] = LDA(0, ks, buf);
      aF[1][ks] = LDA(1, ks, buf);
      bF[0][ks] = LDB(0, ks, buf);
    }
    __builtin_amdgcn_sched_barrier(0);
    __builtin_amdgcn_s_barrier();
    __builtin_amdgcn_sched_barrier(0);
    __builtin_amdgcn_s_setprio(1);
#pragma unroll
    for (int ks = 0; ks < 4; ++ks) {
      acc[0][0] = __builtin_amdgcn_mfma_f32_32x32x16_bf16(aF[0][ks], bF[0][ks], acc[0][0], 0, 0, 0);
      acc[1][0] = __builtin_amdgcn_mfma_f32_32x32x16_bf16(aF[1][ks], bF[0][ks], acc[1][0], 0, 0, 0);
    }
    __builtin_amdgcn_s_setprio(0);
    __builtin_amdgcn_sched_barrier(0);
    __builtin_amdgcn_s_barrier();
    __builtin_amdgcn_sched_barrier(0);

    // ---------- phase 2: quadrant (qm0, nt1) ----------
    if (t + 1 < NT) STAGE(ldsA, aTB, t + 1, 1);
#pragma unroll
    for (int ks = 0; ks < 4; ++ks) bF[1][ks] = LDB(1, ks, buf);
    __builtin_amdgcn_sched_barrier(0);
    __builtin_amdgcn_s_barrier();
    __builtin_amdgcn_sched_barrier(0);
    __builtin_amdgcn_s_setprio(1);
#pragma unroll
    for (int ks = 0; ks < 4; ++ks) {
      acc[0][1] = __builtin_amdgcn_mfma_f32_32x32x16_bf16(aF[0][ks], bF[1][ks], acc[0][1], 0, 0, 0);
      acc[1][1] = __builtin_amdgcn_mfma_f32_32x32x16_bf16(aF[1][ks], bF[1][ks], acc[1][1], 0, 0, 0);
    }
    __builtin_amdgcn_s_setprio(0);
    __builtin_amdgcn_sched_barrier(0);
    __builtin_amdgcn_s_barrier();
    __builtin_amdgcn_sched_barrier(0);

    // ---------- phase 3: quadrant (qm1, nt1) ----------
    if (t + 2 < NT) STAGE(ldsB, bTB, t + 2, 0);
#pragma unroll
    for (int ks = 0; ks < 4; ++ks) {
      aF[0][ks] = LDA(2, ks, buf);
      aF[1][ks] = LDA(3, ks, buf);
    }
    __builtin_amdgcn_sched_barrier(0);
    __builtin_amdgcn_s_barrier();
    __builtin_amdgcn_sched_barrier(0);
    __builtin_amdgcn_s_setprio(1);
#pragma unroll
    for (int ks = 0; ks < 4; ++ks) {
      acc[2][1] = __builtin_amdgcn_mfma_f32_32x32x16_bf16(aF[0][ks], bF[1][ks], acc[2][1], 0, 0, 0);
      acc[3][1] = __builtin_amdgcn_mfma_f32_32x32x16_bf16(aF[1][ks], bF[1][ks], acc[3][1], 0, 0, 0);
    }
    __builtin_amdgcn_s_setprio(0);
    __builtin_amdgcn_sched_barrier(0);
    __builtin_amdgcn_s_barrier();
    __builtin_amdgcn_sched_barrier(0);

    // ---------- phase 4: quadrant (qm1, nt0) + vmcnt checkpoint ----------
    if (t + 2 < NT) STAGE(ldsB, bTB, t + 2, 1);
    if (t < NT - 2) asm volatile("s_waitcnt vmcnt(4)" ::: "memory");
    else            asm volatile("s_waitcnt vmcnt(0)" ::: "memory");
    __builtin_amdgcn_sched_barrier(0);
    __builtin_amdgcn_s_barrier();
    __builtin_amdgcn_sched_barrier(0);
    __builtin_amdgcn_s_setprio(1);
#pragma unroll
    for (int ks = 0; ks < 4; ++ks) {
      acc[2][0] = __builtin_amdgcn_mfma_f32_32x32x16_bf16(aF[0][ks], bF[0][ks], acc[2][0], 0, 0, 0);
      acc[3][0] = __builtin_amdgcn_mfma_f32_32x32x16_bf16(aF[1][ks], bF[0][ks], acc[3][0], 0, 0, 0);
    }
    __builtin_amdgcn_s_setprio(0);
    __builtin_amdgcn_sched_barrier(0);
    __builtin_amdgcn_s_barrier();
    __builtin_amdgcn_sched_barrier(0);
  }
#undef STAGE
#undef LDA
#undef LDB

  // ---- epilogue: C/D col=lane&31, row=(r&3)+8*(r>>2)+4*(lane>>5) ----
#pragma unroll
  for (int mt = 0; mt < 4; ++mt) {
#pragma unroll
    for (int nt = 0; nt < 2; ++nt) {
      const int col = nBase + wn * 64 + nt * 32 + l32;
#pragma unroll
      for (int r = 0; r < 16; ++r) {
        const int row = mBase + wm * 128 + mt * 32 + (r & 3) + 8 * (r >> 2) + 4 * hl;
        if (OUT_BF16)
          ((u16*)Cv)[(size_t)row * N + col] = f2bf(acc[mt][nt][r]);
        else
          ((float*)Cv)[(size_t)row * N + col] = acc[mt][nt][r];
      }
    }
  }
}

// ---------------- causal depthwise conv (K=4) + gating ----------------
#define TT 32
__global__ __launch_bounds__(256) void conv_gate(
    const u16* __restrict__ bcx, const float* __restrict__ convw,
    u16* __restrict__ y, float* __restrict__ states)
{
  const int tid = threadIdx.x;
  const int d8  = tid * 8;
  const int s   = blockIdx.y;
  const int t0  = blockIdx.x * TT;

  float w0[8], w1[8], w2[8], w3[8];
#pragma unroll
  for (int j = 0; j < 8; ++j) {
    float4 wv = *(const float4*)&convw[(d8 + j) * 4];
    w0[j] = wv.x; w1[j] = wv.y; w2[j] = wv.z; w3[j] = wv.w;
  }

  float win0[8], win1[8], win2[8];
  if (t0 == 0) {
#pragma unroll
    for (int j = 0; j < 8; ++j) { win0[j] = 0.f; win1[j] = 0.f; win2[j] = 0.f; }
  } else {
    const u16* r0 = bcx + (size_t)(s * SEQ_LEN + t0 - 3) * N3D + d8;
    bf16x8 b0 = *(const bf16x8*)(r0);
    bf16x8 x0 = *(const bf16x8*)(r0 + 2 * CONV_DIM);
    bf16x8 b1 = *(const bf16x8*)(r0 + N3D);
    bf16x8 x1 = *(const bf16x8*)(r0 + N3D + 2 * CONV_DIM);
    bf16x8 b2 = *(const bf16x8*)(r0 + 2 * N3D);
    bf16x8 x2 = *(const bf16x8*)(r0 + 2 * N3D + 2 * CONV_DIM);
#pragma unroll
    for (int j = 0; j < 8; ++j) {
      win0[j] = (float)b0[j] * (float)x0[j];
      win1[j] = (float)b1[j] * (float)x1[j];
      win2[j] = (float)b2[j] * (float)x2[j];
    }
  }

  for (int t = t0; t < t0 + TT; ++t) {
    const u16* row = bcx + (size_t)(s * SEQ_LEN + t) * N3D + d8;
    bf16x8 bv = *(const bf16x8*)row;
    bf16x8 cv = *(const bf16x8*)(row + CONV_DIM);
    bf16x8 xv = *(const bf16x8*)(row + 2 * CONV_DIM);
    float bx[8];
#pragma unroll
    for (int j = 0; j < 8; ++j) bx[j] = (float)bv[j] * (float)xv[j];

    u32 pk[4];
#pragma unroll
    for (int j = 0; j < 4; ++j) {
      const int a = 2 * j, b = 2 * j + 1;
      float ya = (float)cv[a] * (w0[a]*win0[a] + w1[a]*win1[a] + w2[a]*win2[a] + w3[a]*bx[a]);
      float yb = (float)cv[b] * (w0[b]*win0[b] + w1[b]*win1[b] + w2[b]*win2[b] + w3[b]*bx[b]);
      pk[j] = (u32)f2bf(ya) | ((u32)f2bf(yb) << 16);
    }
    uint4 o; o.x = pk[0]; o.y = pk[1]; o.z = pk[2]; o.w = pk[3];
    *(uint4*)&y[(size_t)(s * SEQ_LEN + t) * CONV_DIM + d8] = o;

    if (t >= SEQ_LEN - 3) {
      float* st = states + (size_t)(s * 3 + (t - (SEQ_LEN - 3))) * CONV_DIM + d8;
      float4 s0v; s0v.x = bx[0]; s0v.y = bx[1]; s0v.z = bx[2]; s0v.w = bx[3];
      float4 s1v; s1v.x = bx[4]; s1v.y = bx[5]; s1v.z = bx[6]; s1v.w = bx[7];
      *(float4*)st = s0v;
      *(float4*)(st + 4) = s1v;
    }
#pragma unroll
    for (int j = 0; j < 8; ++j) { win0[j] = win1[j]; win1[j] = win2[j]; win2[j] = bx[j]; }
  }
}

// ---------------- launch ----------------
extern "C" void kernel_launch(void* const* d_in, const int* in_sizes, int n_in,
                              void* d_out, int out_size, void* d_ws, size_t ws_size,
                              hipStream_t stream)
{
  const float* hidden = (const float*)d_in[0];  // [16384, 2048]
  const float* w_in   = (const float*)d_in[1];  // [6144, 2048]
  const float* convw  = (const float*)d_in[2];  // [2048, 1, 4]
  const float* w_out  = (const float*)d_in[3];  // [2048, 2048]

  char* ws = (char*)d_ws;
  u16* hb  = (u16*)(ws);                          // 33554432 elems (67.1 MB)
  u16* wib = (u16*)(ws + (size_t)67108864);       // 12582912 elems (25.2 MB)
  u16* wob = (u16*)(ws + (size_t)92274688);       //  4194304 elems ( 8.4 MB)
  u16* bcx = (u16*)(ws + (size_t)100663296);      // 16384*6144 elems (201 MB)
  u16* yb  = (u16*)(ws + (size_t)301989888);      // 33554432 elems (67.1 MB)

  float* out    = (float*)d_out;                  // [16384, 2048] fp32
  float* states = out + (size_t)NTOK * HIDDEN;    // [4, 3, 2048] fp32

  cast_f32_bf16<<<32768, 256, 0, stream>>>(hidden, hb, 8388608);
  cast_f32_bf16<<<12288, 256, 0, stream>>>(w_in,  wib, 3145728);
  cast_f32_bf16<<<4096,  256, 0, stream>>>(w_out, wob, 1048576);

  // bcx[N,6144] = hidden @ w_in^T  (bf16 out) — 64 x 24 = 1536 blocks
  gemm256_bt<true><<<dim3(N3D / 256, NTOK / 256), 512, 0, stream>>>(
      hb, wib, bcx, NTOK, N3D, HIDDEN);

  // depthwise conv + gates -> y bf16, states fp32
  conv_gate<<<dim3(SEQ_LEN / TT, NUM_SEQS), 256, 0, stream>>>(bcx, convw, yb, states);

  // out[N,2048] = y @ w_out^T  (fp32 out) — 64 x 8 = 512 blocks
  gemm256_bt<false><<<dim3(CONV_DIM / 256, NTOK / 256), 512, 0, stream>>>(
      yb, wob, out, NTOK, CONV_DIM, CONV_DIM);
}